// Round 12
// baseline (28.649 us; speedup 1.0000x reference)
//
#include <hip/hip_runtime.h>
#include <hip/hip_bf16.h>
#include <math.h>

// y[n,o] = min_i (x[n,i] + w[o,i]) + bias[o]
// x: (32768,128) f32, w: (128,128) f32, bias: (128,) f32, out: (32768,128) f32
//
// f16, BM=128 x BN=64 block, 256 threads, 8x4 per-thread tile (32 outputs).
// Per kc (8 k-elems): 8 x-reads (16-lane BROADCAST, conflict-free) + 4 w-reads
// (16 distinct rows, 2-way = free) = 12 ds_read_b128 per 256 pk-VALU (21:1,
// vs 16:1 in round 10). 32 independent acc chains; 2 waves/SIMD (R11 showed
// occupancy is not the limiter). Single barrier. No pointer/operand arrays
// with runtime indices; all LDS offsets are compile-time immediates.

typedef __fp16 h2 __attribute__((ext_vector_type(2)));
typedef __fp16 h4 __attribute__((ext_vector_type(4)));
typedef __fp16 h8 __attribute__((ext_vector_type(8)));

constexpr int K     = 128;
constexpr int BM    = 128;
constexpr int BN    = 64;
constexpr int LDRH2 = 68;        // row stride in h2 units (272 B, 16B-aligned)

__global__ __launch_bounds__(256, 2)
void minplus_kernel(const float* __restrict__ x,
                    const float* __restrict__ w,
                    const float* __restrict__ bias,
                    float* __restrict__ out)
{
    __shared__ h2 lds[(BM + BN) * LDRH2];    // 52,224 B
    h2* xs = lds;
    h2* ws = lds + BM * LDRH2;

    const int tid = threadIdx.x;
    const int rt  = blockIdx.x & 255;        // row tile (0..255)
    const int ct  = blockIdx.x >> 8;         // col half (0..1), high bit

    const float* xsrc = x + (size_t)rt * BM * K;
    const float* wsrc = w + (size_t)ct * BN * K;

    // ---- stage x (128x128) and w (64x128), f32 -> f16, coalesced ----
    #pragma unroll
    for (int p = 0; p < 16; ++p) {
        int c   = p * 256 + tid;             // float4-chunk id, 0..4095
        int row = c >> 5;                    // 0..127
        int q   = c & 31;
        float4 v = *(const float4*)(xsrc + row * K + q * 4);
        h2 a = __builtin_amdgcn_cvt_pkrtz(v.x, v.y);
        h2 b = __builtin_amdgcn_cvt_pkrtz(v.z, v.w);
        *(h4*)(xs + row * LDRH2 + q * 2) = __builtin_shufflevector(a, b, 0, 1, 2, 3);
    }
    #pragma unroll
    for (int p = 0; p < 8; ++p) {
        int c   = p * 256 + tid;             // 0..2047
        int row = c >> 5;                    // 0..63
        int q   = c & 31;
        float4 v = *(const float4*)(wsrc + row * K + q * 4);
        h2 a = __builtin_amdgcn_cvt_pkrtz(v.x, v.y);
        h2 b = __builtin_amdgcn_cvt_pkrtz(v.z, v.w);
        *(h4*)(ws + row * LDRH2 + q * 2) = __builtin_shufflevector(a, b, 0, 1, 2, 3);
    }
    __syncthreads();                         // the ONLY barrier

    const int ty = tid >> 4;                 // 0..15 : rows ty + 16m, m=0..7
    const int tx = tid & 15;                 // 0..15 : cols tx + 16n, n=0..3
    const h2* xbp = xs + ty * LDRH2;         // broadcast reads (16 lanes/addr)
    const h2* wbp = ws + tx * LDRH2;         // 16 distinct rows, 2-way = free

    h2 hbig;
    hbig.x = (__fp16)65504.0f;
    hbig.y = (__fp16)65504.0f;
    h2 acc[8][4];
    #pragma unroll
    for (int m = 0; m < 8; ++m)
        #pragma unroll
        for (int n = 0; n < 4; ++n)
            acc[m][n] = hbig;

    // ---- 16 chunks of 8 k-elems: 12 ds_read_b128 + 256 pk-VALU each ----
    #pragma unroll 4
    for (int kc = 0; kc < 16; ++kc) {
        h8 xv0 = *(const h8*)(xbp + 0 * 16 * LDRH2 + kc * 4);
        h8 xv1 = *(const h8*)(xbp + 1 * 16 * LDRH2 + kc * 4);
        h8 xv2 = *(const h8*)(xbp + 2 * 16 * LDRH2 + kc * 4);
        h8 xv3 = *(const h8*)(xbp + 3 * 16 * LDRH2 + kc * 4);
        h8 xv4 = *(const h8*)(xbp + 4 * 16 * LDRH2 + kc * 4);
        h8 xv5 = *(const h8*)(xbp + 5 * 16 * LDRH2 + kc * 4);
        h8 xv6 = *(const h8*)(xbp + 6 * 16 * LDRH2 + kc * 4);
        h8 xv7 = *(const h8*)(xbp + 7 * 16 * LDRH2 + kc * 4);
        h8 wv0 = *(const h8*)(wbp + 0 * 16 * LDRH2 + kc * 4);
        h8 wv1 = *(const h8*)(wbp + 1 * 16 * LDRH2 + kc * 4);
        h8 wv2 = *(const h8*)(wbp + 2 * 16 * LDRH2 + kc * 4);
        h8 wv3 = *(const h8*)(wbp + 3 * 16 * LDRH2 + kc * 4);

#define UPD(m, n, XV, WV)                                                     \
        {                                                                     \
            h8 t  = XV + WV;                 /* 4x v_pk_add_f16 */            \
            h2 t0 = __builtin_shufflevector(t, t, 0, 1);                      \
            h2 t1 = __builtin_shufflevector(t, t, 2, 3);                      \
            h2 t2 = __builtin_shufflevector(t, t, 4, 5);                      \
            h2 t3 = __builtin_shufflevector(t, t, 6, 7);                      \
            h2 u  = __builtin_elementwise_min(t0, t1);                        \
            h2 v  = __builtin_elementwise_min(t2, t3);                        \
            h2 uv = __builtin_elementwise_min(u, v);                          \
            acc[m][n] = __builtin_elementwise_min(acc[m][n], uv);             \
        }
        UPD(0, 0, xv0, wv0) UPD(0, 1, xv0, wv1) UPD(0, 2, xv0, wv2) UPD(0, 3, xv0, wv3)
        UPD(1, 0, xv1, wv0) UPD(1, 1, xv1, wv1) UPD(1, 2, xv1, wv2) UPD(1, 3, xv1, wv3)
        UPD(2, 0, xv2, wv0) UPD(2, 1, xv2, wv1) UPD(2, 2, xv2, wv2) UPD(2, 3, xv2, wv3)
        UPD(3, 0, xv3, wv0) UPD(3, 1, xv3, wv1) UPD(3, 2, xv3, wv2) UPD(3, 3, xv3, wv3)
        UPD(4, 0, xv4, wv0) UPD(4, 1, xv4, wv1) UPD(4, 2, xv4, wv2) UPD(4, 3, xv4, wv3)
        UPD(5, 0, xv5, wv0) UPD(5, 1, xv5, wv1) UPD(5, 2, xv5, wv2) UPD(5, 3, xv5, wv3)
        UPD(6, 0, xv6, wv0) UPD(6, 1, xv6, wv1) UPD(6, 2, xv6, wv2) UPD(6, 3, xv6, wv3)
        UPD(7, 0, xv7, wv0) UPD(7, 1, xv7, wv1) UPD(7, 2, xv7, wv2) UPD(7, 3, xv7, wv3)
#undef UPD
    }

    // ---- epilogue: f16 pair-reduce -> f32, + bias, store ----
    const int rowbase = rt * BM + ty;
    const int colbase = ct * BN + tx;
    #pragma unroll
    for (int n = 0; n < 4; ++n) {
        float b = bias[colbase + 16 * n];
        #pragma unroll
        for (int m = 0; m < 8; ++m) {
            h2 a = acc[m][n];
            out[(size_t)(rowbase + 16 * m) * 128 + colbase + 16 * n] =
                fminf((float)a.x, (float)a.y) + b;
        }
    }
}

extern "C" void kernel_launch(void* const* d_in, const int* in_sizes, int n_in,
                              void* d_out, int out_size, void* d_ws, size_t ws_size,
                              hipStream_t stream) {
    const float* x    = (const float*)d_in[0];
    const float* w    = (const float*)d_in[1];
    const float* bias = (const float*)d_in[2];
    float* out = (float*)d_out;

    int nrows  = in_sizes[0] / K;             // 32768
    int blocks = (nrows / BM) * (K / BN);     // 512
    minplus_kernel<<<blocks, 256, 0, stream>>>(x, w, bias, out);
}